// Round 7
// baseline (262.027 us; speedup 1.0000x reference)
//
#include <hip/hip_runtime.h>

typedef __bf16 bf16x8 __attribute__((ext_vector_type(8)));
typedef float  f32x4  __attribute__((ext_vector_type(4)));
typedef unsigned int uint;

__device__ inline unsigned short f2bf(float f) {
  union { float f; unsigned int u; } v; v.f = f;
  unsigned int u = v.u;
  unsigned int r = u + 0x7FFF + ((u >> 16) & 1);   // RNE
  return (unsigned short)(r >> 16);
}

// pack two floats to packed bf16x2 with round-half-up (err <= 0.5 ulp)
__device__ inline uint pack_bf16_rhu(float a, float b) {
  uint ua = __builtin_bit_cast(uint, a) + 0x8000u;
  uint ub = __builtin_bit_cast(uint, b) + 0x8000u;
  return __builtin_amdgcn_perm(ub, ua, 0x07060302u);
}

__device__ inline void load_lds16(const unsigned short* g, unsigned short* l) {
  __builtin_amdgcn_global_load_lds(
      (const __attribute__((address_space(1))) uint*)(g),
      (__attribute__((address_space(3))) uint*)(l), 16, 0, 0);
}

// ---------------------------------------------------------------- fused convert
__device__ inline void cvt4(const float* in, unsigned short* out) {
  float4 f = *reinterpret_cast<const float4*>(in);
  ushort4 o;
  o.x = f2bf(f.x); o.y = f2bf(f.y); o.z = f2bf(f.z); o.w = f2bf(f.w);
  *reinterpret_cast<ushort4*>(out) = o;
}

__global__ void cvt_all(const float* __restrict__ x, const float* __restrict__ w_in,
                        const float* __restrict__ w_out,
                        unsigned short* __restrict__ x_bf,
                        unsigned short* __restrict__ w_in_bf,
                        unsigned short* __restrict__ w_out_bf) {
  const int n1 = 8192 * 1024, n2 = 3072 * 1024;
  int i = (blockIdx.x * blockDim.x + threadIdx.x) * 4;
  if (i < n1)            cvt4(x + i, x_bf + i);
  else if (i < n1 + n2)  cvt4(w_in + (i - n1), w_in_bf + (i - n1));
  else                   cvt4(w_out + (i - n1 - n2), w_out_bf + (i - n1 - n2));
}

// ---------------------------------------------------------------- GEMM  C = A * B^T + bias
// R2-verified m97 structure (single 32 KB buffer, stage-after, 2 barriers/tile)
// -- measured 68.8 us / 749 TF on gemm1; the structure ceiling for this shape.
// VSPLIT: cols < 2048 -> row-major Cout, cols >= 2048 (V) -> transposed vt[bh][d][s].
template<bool OUT_BF16, bool VSPLIT>
__global__ __launch_bounds__(256) void gemm_bt128(
    const unsigned short* __restrict__ A,
    const unsigned short* __restrict__ B,
    const float* __restrict__ bias,
    void* __restrict__ Cout,
    unsigned short* __restrict__ vt,
    int M, int N, int K, int ldc, float scale, int ncut)
{
  __shared__ __attribute__((aligned(16))) unsigned short As[128 * 64];
  __shared__ __attribute__((aligned(16))) unsigned short Bs[128 * 64];

  const int t    = threadIdx.x;
  const int wave = t >> 6, lane = t & 63;
  const int l16  = lane & 15, quad = lane >> 4;
  const int wr = wave >> 1, wc = wave & 1;
  const int m0 = blockIdx.y * 128, n0 = blockIdx.x * 128;
  const int l8 = l16 & 7;

  f32x4 acc[4][4] = {};

  for (int k0 = 0; k0 < K; k0 += 64) {
#pragma unroll
    for (int i = 0; i < 4; ++i) {
      int chunk = i * 256 + t;
      int row = chunk >> 3, cb = chunk & 7;
      int gcb = cb ^ (row & 7);
      load_lds16(A + (size_t)(m0 + row) * K + k0 + gcb * 8, As + chunk * 8);
    }
#pragma unroll
    for (int i = 0; i < 4; ++i) {
      int chunk = i * 256 + t;
      int row = chunk >> 3, cb = chunk & 7;
      int gcb = cb ^ (row & 7);
      load_lds16(B + (size_t)(n0 + row) * K + k0 + gcb * 8, Bs + chunk * 8);
    }
    __syncthreads();
#pragma unroll
    for (int ks = 0; ks < 2; ++ks) {
      bf16x8 af[4], bfr[4];
#pragma unroll
      for (int mt = 0; mt < 4; ++mt)
        af[mt] = *(const bf16x8*)(As + (wr * 64 + mt * 16 + l16) * 64 +
                                  (((ks * 4 + quad) ^ l8) << 3));
#pragma unroll
      for (int nt = 0; nt < 4; ++nt)
        bfr[nt] = *(const bf16x8*)(Bs + (wc * 64 + nt * 16 + l16) * 64 +
                                   (((ks * 4 + quad) ^ l8) << 3));
#pragma unroll
      for (int mt = 0; mt < 4; ++mt)
#pragma unroll
        for (int nt = 0; nt < 4; ++nt)
          acc[mt][nt] = __builtin_amdgcn_mfma_f32_16x16x32_bf16(af[mt], bfr[nt], acc[mt][nt], 0, 0, 0);
    }
    __syncthreads();
  }

#pragma unroll
  for (int nt = 0; nt < 4; ++nt) {
    int col = n0 + wc * 64 + nt * 16 + l16;
    float bv = bias[col];
    float mlt = (col < ncut) ? scale : 1.0f;
#pragma unroll
    for (int mt = 0; mt < 4; ++mt) {
      int row0 = m0 + wr * 64 + mt * 16 + quad * 4;
      float v0 = (acc[mt][nt][0] + bv) * mlt;
      float v1 = (acc[mt][nt][1] + bv) * mlt;
      float v2 = (acc[mt][nt][2] + bv) * mlt;
      float v3 = (acc[mt][nt][3] + bv) * mlt;
      if (VSPLIT && col >= 2048) {
        int d = col - 2048, h = d >> 6, dd = d & 63;
        int bb = row0 >> 11, s = row0 & 2047;
        uint2 w;
        w.x = pack_bf16_rhu(v0, v1);
        w.y = pack_bf16_rhu(v2, v3);
        *(uint2*)(vt + ((size_t)((bb * 16 + h) * 64 + dd) * 2048 + s)) = w;
      } else {
#pragma unroll
        for (int r = 0; r < 4; ++r) {
          float v = (r == 0) ? v0 : (r == 1) ? v1 : (r == 2) ? v2 : v3;
          if (OUT_BF16)
            ((unsigned short*)Cout)[(size_t)(row0 + r) * ldc + col] = f2bf(v);
          else
            ((float*)Cout)[(size_t)(row0 + r) * ldc + col] = v;
        }
      }
    }
  }
}

// ---------------------------------------------------------------- flash attention
// 128-row Q-tile, FOUR waves (256 threads), 32 Q-ROWS PER WAVE (2 x 16-row
// groups in registers). Rationale: attn is LDS-BW-bound; K/V fragment reads
// are identical across waves, so feeding 2 Q-groups from one kf/vf b128 read
// cuts block LDS traffic/tile from 176 KB to 112 KB (-36%).
// PAIRED Q-TILES (qt=15-pair then pair -> uniform 34 KV tiles/block),
// 512 blocks = 2/CU. K/V LDS double-buffered, ONE barrier per KV tile.
// All LDS tiles unpadded, unified XOR granule swizzle:
//   slot(row, G) = row*64 + ((G ^ (row&7)) << 3)   (row offsets +32/+64 keep row&7)
__global__ __launch_bounds__(256) void attn(
    const unsigned short* __restrict__ qkv2,   // (B*S) x 2048 : Q|K
    const unsigned short* __restrict__ vt,     // [bh][d][s]
    unsigned short* __restrict__ y,
    const int* __restrict__ flag)
{
  __shared__ __attribute__((aligned(16))) unsigned short Qs[128 * 64];      // 16 KB, reused as Ps
  __shared__ __attribute__((aligned(16))) unsigned short Ks[2][64 * 64];    // 16 KB
  __shared__ __attribute__((aligned(16))) unsigned short Vs[2][64 * 64];    // 16 KB

  const int t    = threadIdx.x;
  const int wave = t >> 6, lane = t & 63;          // wave 0..3
  const int l16  = lane & 15, quad = lane >> 4;
  const int l8   = l16 & 7;
  const int idx  = blockIdx.x;
  const int bh   = idx & 63;
  const int pair = idx >> 6;                  // 0..7
  const int b = bh >> 4, h = bh & 15;
  const int causal = flag[0];

  const unsigned short* Qg  = qkv2 + (size_t)b * 2048 * 2048 + h * 64;
  const unsigned short* Kg  = Qg + 1024;
  const unsigned short* Vtg = vt + (size_t)bh * 64 * 2048;

  // Q staging coords: rows sr and sr+64, granules sg, sg+1 (4 uint4 per thread)
  const int sr = t >> 2, sg = (t & 3) * 2;
  const int slot0 = sr * 64 + (((sg    ) ^ (sr & 7)) << 3);
  const int slot1 = sr * 64 + (((sg + 1) ^ (sr & 7)) << 3);
  // K / V^T staging: rows kr and kr+32, granule kg (2 uint4 per thread each)
  const int kr = t >> 3, kg = t & 7;
  const int kslot = kr * 64 + ((kg ^ (kr & 7)) << 3);

  unsigned short* Ps = Qs;

  for (int half = 0; half < 2; ++half) {
    const int qt = half ? pair : (15 - pair);   // heavy tile first
    const int q0 = qt * 128;
    const int jmax = causal ? 2 * qt + 1 : 31;

    // ---- prefetch K/V tile 0, stage Q tile (swizzled)
    const unsigned short* kptr = Kg + (size_t)kr * 2048 + kg * 8;
    const unsigned short* vptr = Vtg + (size_t)kr * 2048 + kg * 8;
    uint4 kreg0 = *(const uint4*)kptr;
    uint4 kreg1 = *(const uint4*)(kptr + 32 * 2048);
    uint4 vreg0 = *(const uint4*)vptr;
    uint4 vreg1 = *(const uint4*)(vptr + 32 * 2048);
    {
      const unsigned short* src  = Qg + (size_t)(q0 + sr) * 2048 + sg * 8;
      const unsigned short* src2 = src + 64 * 2048;
      *(uint4*)(Qs + slot0)        = *(const uint4*)src;
      *(uint4*)(Qs + slot1)        = *(const uint4*)(src + 8);
      *(uint4*)(Qs + slot0 + 4096) = *(const uint4*)src2;
      *(uint4*)(Qs + slot1 + 4096) = *(const uint4*)(src2 + 8);
    }
    __syncthreads();
    bf16x8 qf[2][2];   // [q-group][ks]
#pragma unroll
    for (int g = 0; g < 2; ++g)
#pragma unroll
      for (int ks = 0; ks < 2; ++ks)
        qf[g][ks] = *(const bf16x8*)(Qs + (wave * 32 + g * 16 + l16) * 64 +
                                     (((ks * 4 + quad) ^ l8) << 3));
    __syncthreads();                 // Qs becomes Ps

    // ---- prologue: write tile 0 to buf0, prefetch tile 1
    *(uint4*)(Ks[0] + kslot)        = kreg0;
    *(uint4*)(Ks[0] + kslot + 2048) = kreg1;
    *(uint4*)(Vs[0] + kslot)        = vreg0;
    *(uint4*)(Vs[0] + kslot + 2048) = vreg1;
    kptr += 64 * 2048;
    vptr += 64;
    if (jmax > 0) {
      kreg0 = *(const uint4*)kptr;
      kreg1 = *(const uint4*)(kptr + 32 * 2048);
      vreg0 = *(const uint4*)vptr;
      vreg1 = *(const uint4*)(vptr + 32 * 2048);
    }
    __syncthreads();

    f32x4 ot[2][4] = {};
    float l_lane[2] = {0.f, 0.f};
    const int q_glob = q0 + wave * 32 + l16;        // group 0; group 1 = +16
    const int wq_max = q0 + wave * 32 + 31;         // last q row owned by this wave

    for (int j = 0; j <= jmax; ++j) {
      const int cur = j & 1;
      // write next tile (regs prefetched a full iteration ago), prefetch j+2
      if (j < jmax) {
        *(uint4*)(Ks[cur ^ 1] + kslot)        = kreg0;
        *(uint4*)(Ks[cur ^ 1] + kslot + 2048) = kreg1;
        *(uint4*)(Vs[cur ^ 1] + kslot)        = vreg0;
        *(uint4*)(Vs[cur ^ 1] + kslot + 2048) = vreg1;
        if (j + 1 < jmax) {
          kptr += 64 * 2048;
          vptr += 64;
          kreg0 = *(const uint4*)kptr;
          kreg1 = *(const uint4*)(kptr + 32 * 2048);
          vreg0 = *(const uint4*)vptr;
          vreg1 = *(const uint4*)(vptr + 32 * 2048);
        }
      }

      // waves whose 32 q rows lie entirely above this KV tile skip compute
      const bool active = !causal || ((j << 6) <= wq_max);
      if (active) {
        // ---- S^T = K * Q^T : one kf read feeds both q-groups
        f32x4 st[2][4] = {};
        __builtin_amdgcn_s_setprio(1);
#pragma unroll
        for (int ks = 0; ks < 2; ++ks) {
#pragma unroll
          for (int mt = 0; mt < 4; ++mt) {
            bf16x8 kf = *(const bf16x8*)(Ks[cur] + (mt * 16 + l16) * 64 +
                                         (((ks * 4 + quad) ^ l8) << 3));
            st[0][mt] = __builtin_amdgcn_mfma_f32_16x16x32_bf16(kf, qf[0][ks], st[0][mt], 0, 0, 0);
            st[1][mt] = __builtin_amdgcn_mfma_f32_16x16x32_bf16(kf, qf[1][ks], st[1][mt], 0, 0, 0);
          }
        }
        __builtin_amdgcn_s_setprio(0);

        // ---- softmax (pre-scaled scores; no max-sub), pack P (swizzled b64 writes)
        const int kv0 = j << 6;
#pragma unroll
        for (int g = 0; g < 2; ++g) {
          const int qg = q_glob + g * 16;
          const bool diag = (causal != 0) && (kv0 + 63 > qg);
          const int prow = (wave * 32 + g * 16 + l16) * 64;
#pragma unroll
          for (int mt = 0; mt < 4; ++mt) {
            float p[4];
#pragma unroll
            for (int r = 0; r < 4; ++r) {
              float pv = __builtin_amdgcn_exp2f(st[g][mt][r]);
              if (diag) {
                int kv = kv0 + mt * 16 + quad * 4 + r;
                if (kv > qg) pv = 0.f;
              }
              p[r] = pv;
            }
            l_lane[g] += (p[0] + p[1]) + (p[2] + p[3]);
            uint2 w;
            w.x = pack_bf16_rhu(p[0], p[1]);
            w.y = pack_bf16_rhu(p[2], p[3]);
            *(uint2*)(Ps + prow +
                      ((((mt * 2 + (quad >> 1)) ^ l8) << 3) + (quad & 1) * 4)) = w;
          }
        }
        __threadfence_block();

        // ---- O^T += V^T * P^T : one vf read feeds both q-groups
        __builtin_amdgcn_s_setprio(1);
#pragma unroll
        for (int ks = 0; ks < 2; ++ks) {
          const int gofs = ((ks * 4 + quad) ^ l8) << 3;
          bf16x8 pf0 = *(const bf16x8*)(Ps + (wave * 32 + l16) * 64 + gofs);
          bf16x8 pf1 = *(const bf16x8*)(Ps + (wave * 32 + 16 + l16) * 64 + gofs);
#pragma unroll
          for (int mt = 0; mt < 4; ++mt) {
            bf16x8 vf = *(const bf16x8*)(Vs[cur] + (mt * 16 + l16) * 64 + gofs);
            ot[0][mt] = __builtin_amdgcn_mfma_f32_16x16x32_bf16(vf, pf0, ot[0][mt], 0, 0, 0);
            ot[1][mt] = __builtin_amdgcn_mfma_f32_16x16x32_bf16(vf, pf1, ot[1][mt], 0, 0, 0);
          }
        }
        __builtin_amdgcn_s_setprio(0);
      }
      __syncthreads();
    }

    // ---- finalize
#pragma unroll
    for (int g = 0; g < 2; ++g) {
      float l = l_lane[g];
      l += __shfl_xor(l, 16);
      l += __shfl_xor(l, 32);
      float inv = 1.f / l;
      const int prow = (wave * 32 + g * 16 + l16) * 64;
#pragma unroll
      for (int mt = 0; mt < 4; ++mt) {
        uint2 w;
        w.x = pack_bf16_rhu(ot[g][mt][0] * inv, ot[g][mt][1] * inv);
        w.y = pack_bf16_rhu(ot[g][mt][2] * inv, ot[g][mt][3] * inv);
        *(uint2*)(Ps + prow +
                  ((((mt * 2 + (quad >> 1)) ^ l8) << 3) + (quad & 1) * 4)) = w;
      }
    }
    __syncthreads();
    {
      size_t base0 = ((size_t)b * 2048 + q0 + sr) * 1024 + h * 64 + sg * 8;
      size_t base1 = base0 + (size_t)64 * 1024;
      *(uint4*)(y + base0)     = *(const uint4*)(Ps + slot0);
      *(uint4*)(y + base0 + 8) = *(const uint4*)(Ps + slot1);
      *(uint4*)(y + base1)     = *(const uint4*)(Ps + slot0 + 4096);
      *(uint4*)(y + base1 + 8) = *(const uint4*)(Ps + slot1 + 4096);
    }
    __syncthreads();   // Ps fully consumed before next half re-stages Qs
  }
}

// ---------------------------------------------------------------- launch
extern "C" void kernel_launch(void* const* d_in, const int* in_sizes, int n_in,
                              void* d_out, int out_size, void* d_ws, size_t ws_size,
                              hipStream_t stream) {
  const float* x     = (const float*)d_in[0];
  const float* w_in  = (const float*)d_in[1];
  const float* b_in  = (const float*)d_in[2];
  const float* w_out = (const float*)d_in[3];
  const float* b_out = (const float*)d_in[4];
  const int*   cmask = (const int*)d_in[5];

  char* ws = (char*)d_ws;
  unsigned short* x_bf     = (unsigned short*)(ws);               // 8192x1024  (16 MB)
  unsigned short* w_in_bf  = (unsigned short*)(ws + 16777216);    // 3072x1024  (6 MB)
  unsigned short* w_out_bf = (unsigned short*)(ws + 23068672);    // 1024x1024  (2 MB)
  unsigned short* qkv2_bf  = (unsigned short*)(ws + 25165824);    // 8192x2048 Q|K (32 MB)
  unsigned short* vt_bf    = (unsigned short*)(ws + 58720256);    // 64bh x 64d x 2048s (16 MB)
  unsigned short* y_bf     = (unsigned short*)(ws + 75497472);    // 8192x1024  (16 MB)

  const int ntot = (8192 + 3072 + 1024) * 1024;
  cvt_all<<<dim3(ntot / 4 / 256), 256, 0, stream>>>(x, w_in, w_out, x_bf, w_in_bf, w_out_bf);

  // QKV = x * w_in^T + b_in ; Q cols pre-scaled; Q|K -> qkv2 row-major, V -> vt transposed
  gemm_bt128<true, true><<<dim3(24, 64), 256, 0, stream>>>(
      x_bf, w_in_bf, b_in, qkv2_bf, vt_bf, 8192, 3072, 1024, 2048,
      0.18033688011112042f, 1024);

  // flash attention -> y_bf (8192 x 1024)
  attn<<<dim3(512), 256, 0, stream>>>(qkv2_bf, vt_bf, y_bf, cmask);

  // out = y * w_out^T + b_out -> fp32 d_out
  gemm_bt128<false, false><<<dim3(8, 64), 256, 0, stream>>>(
      y_bf, w_out_bf, b_out, d_out, nullptr, 8192, 1024, 1024, 1024, 1.0f, 0);
}

// Round 8
// 258.787 us; speedup vs baseline: 1.0125x; 1.0125x over previous
//
#include <hip/hip_runtime.h>

typedef __bf16 bf16x8 __attribute__((ext_vector_type(8)));
typedef float  f32x4  __attribute__((ext_vector_type(4)));
typedef unsigned int uint;

__device__ inline unsigned short f2bf(float f) {
  union { float f; unsigned int u; } v; v.f = f;
  unsigned int u = v.u;
  unsigned int r = u + 0x7FFF + ((u >> 16) & 1);   // RNE
  return (unsigned short)(r >> 16);
}

// pack two floats to packed bf16x2 with round-half-up (err <= 0.5 ulp)
__device__ inline uint pack_bf16_rhu(float a, float b) {
  uint ua = __builtin_bit_cast(uint, a) + 0x8000u;
  uint ub = __builtin_bit_cast(uint, b) + 0x8000u;
  return __builtin_amdgcn_perm(ub, ua, 0x07060302u);
}

__device__ inline void load_lds16(const unsigned short* g, unsigned short* l) {
  __builtin_amdgcn_global_load_lds(
      (const __attribute__((address_space(1))) uint*)(g),
      (__attribute__((address_space(3))) uint*)(l), 16, 0, 0);
}

// ---------------------------------------------------------------- fused convert
__device__ inline void cvt4(const float* in, unsigned short* out) {
  float4 f = *reinterpret_cast<const float4*>(in);
  ushort4 o;
  o.x = f2bf(f.x); o.y = f2bf(f.y); o.z = f2bf(f.z); o.w = f2bf(f.w);
  *reinterpret_cast<ushort4*>(out) = o;
}

__global__ void cvt_all(const float* __restrict__ x, const float* __restrict__ w_in,
                        const float* __restrict__ w_out,
                        unsigned short* __restrict__ x_bf,
                        unsigned short* __restrict__ w_in_bf,
                        unsigned short* __restrict__ w_out_bf) {
  const int n1 = 8192 * 1024, n2 = 3072 * 1024;
  int i = (blockIdx.x * blockDim.x + threadIdx.x) * 4;
  if (i < n1)            cvt4(x + i, x_bf + i);
  else if (i < n1 + n2)  cvt4(w_in + (i - n1), w_in_bf + (i - n1));
  else                   cvt4(w_out + (i - n1 - n2), w_out_bf + (i - n1 - n2));
}

// ---------------------------------------------------------------- GEMM  C = A * B^T + bias
// R2-verified m97 structure (single 32 KB buffer, stage-after, 2 barriers/tile)
// -- measured 68.8 us / 749 TF on gemm1; the structure ceiling for this shape.
// VSPLIT: cols < 2048 -> row-major Cout, cols >= 2048 (V) -> transposed vt[bh][d][s].
template<bool OUT_BF16, bool VSPLIT>
__global__ __launch_bounds__(256) void gemm_bt128(
    const unsigned short* __restrict__ A,
    const unsigned short* __restrict__ B,
    const float* __restrict__ bias,
    void* __restrict__ Cout,
    unsigned short* __restrict__ vt,
    int M, int N, int K, int ldc, float scale, int ncut)
{
  __shared__ __attribute__((aligned(16))) unsigned short As[128 * 64];
  __shared__ __attribute__((aligned(16))) unsigned short Bs[128 * 64];

  const int t    = threadIdx.x;
  const int wave = t >> 6, lane = t & 63;
  const int l16  = lane & 15, quad = lane >> 4;
  const int wr = wave >> 1, wc = wave & 1;
  const int m0 = blockIdx.y * 128, n0 = blockIdx.x * 128;
  const int l8 = l16 & 7;

  f32x4 acc[4][4] = {};

  for (int k0 = 0; k0 < K; k0 += 64) {
#pragma unroll
    for (int i = 0; i < 4; ++i) {
      int chunk = i * 256 + t;
      int row = chunk >> 3, cb = chunk & 7;
      int gcb = cb ^ (row & 7);
      load_lds16(A + (size_t)(m0 + row) * K + k0 + gcb * 8, As + chunk * 8);
    }
#pragma unroll
    for (int i = 0; i < 4; ++i) {
      int chunk = i * 256 + t;
      int row = chunk >> 3, cb = chunk & 7;
      int gcb = cb ^ (row & 7);
      load_lds16(B + (size_t)(n0 + row) * K + k0 + gcb * 8, Bs + chunk * 8);
    }
    __syncthreads();
#pragma unroll
    for (int ks = 0; ks < 2; ++ks) {
      bf16x8 af[4], bfr[4];
#pragma unroll
      for (int mt = 0; mt < 4; ++mt)
        af[mt] = *(const bf16x8*)(As + (wr * 64 + mt * 16 + l16) * 64 +
                                  (((ks * 4 + quad) ^ l8) << 3));
#pragma unroll
      for (int nt = 0; nt < 4; ++nt)
        bfr[nt] = *(const bf16x8*)(Bs + (wc * 64 + nt * 16 + l16) * 64 +
                                   (((ks * 4 + quad) ^ l8) << 3));
#pragma unroll
      for (int mt = 0; mt < 4; ++mt)
#pragma unroll
        for (int nt = 0; nt < 4; ++nt)
          acc[mt][nt] = __builtin_amdgcn_mfma_f32_16x16x32_bf16(af[mt], bfr[nt], acc[mt][nt], 0, 0, 0);
    }
    __syncthreads();
  }

#pragma unroll
  for (int nt = 0; nt < 4; ++nt) {
    int col = n0 + wc * 64 + nt * 16 + l16;
    float bv = bias[col];
    float mlt = (col < ncut) ? scale : 1.0f;
#pragma unroll
    for (int mt = 0; mt < 4; ++mt) {
      int row0 = m0 + wr * 64 + mt * 16 + quad * 4;
      float v0 = (acc[mt][nt][0] + bv) * mlt;
      float v1 = (acc[mt][nt][1] + bv) * mlt;
      float v2 = (acc[mt][nt][2] + bv) * mlt;
      float v3 = (acc[mt][nt][3] + bv) * mlt;
      if (VSPLIT && col >= 2048) {
        int d = col - 2048, h = d >> 6, dd = d & 63;
        int bb = row0 >> 11, s = row0 & 2047;
        uint2 w;
        w.x = pack_bf16_rhu(v0, v1);
        w.y = pack_bf16_rhu(v2, v3);
        *(uint2*)(vt + ((size_t)((bb * 16 + h) * 64 + dd) * 2048 + s)) = w;
      } else {
#pragma unroll
        for (int r = 0; r < 4; ++r) {
          float v = (r == 0) ? v0 : (r == 1) ? v1 : (r == 2) ? v2 : v3;
          if (OUT_BF16)
            ((unsigned short*)Cout)[(size_t)(row0 + r) * ldc + col] = f2bf(v);
          else
            ((float*)Cout)[(size_t)(row0 + r) * ldc + col] = v;
        }
      }
    }
  }
}

// ---------------------------------------------------------------- flash attention
// 256-row Q-tile, EIGHT waves (512 threads), 32 Q-ROWS PER WAVE (2 x 16-row
// groups). Amortization at constant TLP: one kf/vf b128 read feeds both
// q-groups -> per-16q LDS traffic 12 b128 vs R2's 22 (-45%), while keeping
// 2 blocks/CU x 8 waves = 16 waves/CU (R7's failure was dropping to 8).
// 8 qt x 64 bh = 512 blocks. qt map g<4 ? 7-g : g-4 puts complementary-work
// blocks at idx and idx+256 (same CU under round-robin placement, sum = 36
// tiles uniform), heavy tiles first.
// K/V LDS double-buffered, ONE barrier per KV tile.
// All LDS tiles unpadded, unified XOR granule swizzle:
//   slot(row, G) = row*64 + ((G ^ (row&7)) << 3)   (row offsets keep row&7)
__global__ __launch_bounds__(512) void attn(
    const unsigned short* __restrict__ qkv2,   // (B*S) x 2048 : Q|K
    const unsigned short* __restrict__ vt,     // [bh][d][s]
    unsigned short* __restrict__ y,
    const int* __restrict__ flag)
{
  __shared__ __attribute__((aligned(16))) unsigned short Qs[256 * 64];      // 32 KB, reused as Ps
  __shared__ __attribute__((aligned(16))) unsigned short Ks[2][64 * 64];    // 16 KB
  __shared__ __attribute__((aligned(16))) unsigned short Vs[2][64 * 64];    // 16 KB

  const int t    = threadIdx.x;
  const int wave = t >> 6, lane = t & 63;          // wave 0..7
  const int l16  = lane & 15, quad = lane >> 4;
  const int l8   = l16 & 7;
  const int idx  = blockIdx.x;
  const int bh   = idx & 63;
  const int g8   = idx >> 6;                       // 0..7
  const int qt   = (g8 < 4) ? (7 - g8) : (g8 - 4); // complementary pairing
  const int b = bh >> 4, h = bh & 15;
  const int causal = flag[0];
  const int q0 = qt * 256;
  const int jmax = causal ? 4 * qt + 3 : 31;

  const unsigned short* Qg  = qkv2 + (size_t)b * 2048 * 2048 + h * 64;
  const unsigned short* Kg  = Qg + 1024;
  const unsigned short* Vtg = vt + (size_t)bh * 64 * 2048;

  // Q staging coords: rows sr and sr+128, granules sg, sg+1 (4 uint4/thread)
  const int sr = t >> 2, sg = (t & 3) * 2;
  const int slot0 = sr * 64 + (((sg    ) ^ (sr & 7)) << 3);
  const int slot1 = sr * 64 + (((sg + 1) ^ (sr & 7)) << 3);
  // K / V^T staging: row kr, granule kg (1 uint4/thread each)
  const int kr = t >> 3, kg = t & 7;
  const int kslot = kr * 64 + ((kg ^ (kr & 7)) << 3);

  unsigned short* Ps = Qs;

  // ---- prefetch K/V tile 0, stage Q tile (swizzled)
  const unsigned short* kptr = Kg + (size_t)kr * 2048 + kg * 8;
  const unsigned short* vptr = Vtg + (size_t)kr * 2048 + kg * 8;
  uint4 kreg = *(const uint4*)kptr;
  uint4 vreg = *(const uint4*)vptr;
  {
    const unsigned short* src  = Qg + (size_t)(q0 + sr) * 2048 + sg * 8;
    const unsigned short* src2 = src + (size_t)128 * 2048;
    *(uint4*)(Qs + slot0)        = *(const uint4*)src;
    *(uint4*)(Qs + slot1)        = *(const uint4*)(src + 8);
    *(uint4*)(Qs + slot0 + 8192) = *(const uint4*)src2;
    *(uint4*)(Qs + slot1 + 8192) = *(const uint4*)(src2 + 8);
  }
  __syncthreads();
  bf16x8 qf[2][2];   // [q-group][ks]
#pragma unroll
  for (int g = 0; g < 2; ++g)
#pragma unroll
    for (int ks = 0; ks < 2; ++ks)
      qf[g][ks] = *(const bf16x8*)(Qs + (wave * 32 + g * 16 + l16) * 64 +
                                   (((ks * 4 + quad) ^ l8) << 3));
  __syncthreads();                 // Qs becomes Ps

  // ---- prologue: write tile 0 to buf0, prefetch tile 1
  *(uint4*)(Ks[0] + kslot) = kreg;
  *(uint4*)(Vs[0] + kslot) = vreg;
  kptr += 64 * 2048;
  vptr += 64;
  if (jmax > 0) {
    kreg = *(const uint4*)kptr;
    vreg = *(const uint4*)vptr;
  }
  __syncthreads();

  f32x4 ot[2][4] = {};
  float l_lane[2] = {0.f, 0.f};
  const int q_glob = q0 + wave * 32 + l16;        // group 0; group 1 = +16
  const int wq_max = q0 + wave * 32 + 31;         // last q row owned by this wave

  for (int j = 0; j <= jmax; ++j) {
    const int cur = j & 1;
    // write next tile (regs prefetched a full iteration ago), prefetch j+2
    if (j < jmax) {
      *(uint4*)(Ks[cur ^ 1] + kslot) = kreg;
      *(uint4*)(Vs[cur ^ 1] + kslot) = vreg;
      if (j + 1 < jmax) {
        kptr += 64 * 2048;
        vptr += 64;
        kreg = *(const uint4*)kptr;
        vreg = *(const uint4*)vptr;
      }
    }

    // waves whose 32 q rows lie entirely above this KV tile skip compute
    const bool active = !causal || ((j << 6) <= wq_max);
    if (active) {
      // ---- S^T = K * Q^T : one kf read feeds both q-groups
      f32x4 st[2][4] = {};
      __builtin_amdgcn_s_setprio(1);
#pragma unroll
      for (int ks = 0; ks < 2; ++ks) {
#pragma unroll
        for (int mt = 0; mt < 4; ++mt) {
          bf16x8 kf = *(const bf16x8*)(Ks[cur] + (mt * 16 + l16) * 64 +
                                       (((ks * 4 + quad) ^ l8) << 3));
          st[0][mt] = __builtin_amdgcn_mfma_f32_16x16x32_bf16(kf, qf[0][ks], st[0][mt], 0, 0, 0);
          st[1][mt] = __builtin_amdgcn_mfma_f32_16x16x32_bf16(kf, qf[1][ks], st[1][mt], 0, 0, 0);
        }
      }
      __builtin_amdgcn_s_setprio(0);

      // ---- softmax (pre-scaled scores; no max-sub), pack P (swizzled b64 writes)
      const int kv0 = j << 6;
#pragma unroll
      for (int g = 0; g < 2; ++g) {
        const int qg = q_glob + g * 16;
        const bool diag = (causal != 0) && (kv0 + 63 > qg);
        const int prow = (wave * 32 + g * 16 + l16) * 64;
#pragma unroll
        for (int mt = 0; mt < 4; ++mt) {
          float p[4];
#pragma unroll
          for (int r = 0; r < 4; ++r) {
            float pv = __builtin_amdgcn_exp2f(st[g][mt][r]);
            if (diag) {
              int kv = kv0 + mt * 16 + quad * 4 + r;
              if (kv > qg) pv = 0.f;
            }
            p[r] = pv;
          }
          l_lane[g] += (p[0] + p[1]) + (p[2] + p[3]);
          uint2 w;
          w.x = pack_bf16_rhu(p[0], p[1]);
          w.y = pack_bf16_rhu(p[2], p[3]);
          *(uint2*)(Ps + prow +
                    ((((mt * 2 + (quad >> 1)) ^ l8) << 3) + (quad & 1) * 4)) = w;
        }
      }
      __threadfence_block();

      // ---- O^T += V^T * P^T : one vf read feeds both q-groups
      __builtin_amdgcn_s_setprio(1);
#pragma unroll
      for (int ks = 0; ks < 2; ++ks) {
        const int gofs = ((ks * 4 + quad) ^ l8) << 3;
        bf16x8 pf0 = *(const bf16x8*)(Ps + (wave * 32 + l16) * 64 + gofs);
        bf16x8 pf1 = *(const bf16x8*)(Ps + (wave * 32 + 16 + l16) * 64 + gofs);
#pragma unroll
        for (int mt = 0; mt < 4; ++mt) {
          bf16x8 vf = *(const bf16x8*)(Vs[cur] + (mt * 16 + l16) * 64 + gofs);
          ot[0][mt] = __builtin_amdgcn_mfma_f32_16x16x32_bf16(vf, pf0, ot[0][mt], 0, 0, 0);
          ot[1][mt] = __builtin_amdgcn_mfma_f32_16x16x32_bf16(vf, pf1, ot[1][mt], 0, 0, 0);
        }
      }
      __builtin_amdgcn_s_setprio(0);
    }
    __syncthreads();
  }

  // ---- finalize
#pragma unroll
  for (int g = 0; g < 2; ++g) {
    float l = l_lane[g];
    l += __shfl_xor(l, 16);
    l += __shfl_xor(l, 32);
    float inv = 1.f / l;
    const int prow = (wave * 32 + g * 16 + l16) * 64;
#pragma unroll
    for (int mt = 0; mt < 4; ++mt) {
      uint2 w;
      w.x = pack_bf16_rhu(ot[g][mt][0] * inv, ot[g][mt][1] * inv);
      w.y = pack_bf16_rhu(ot[g][mt][2] * inv, ot[g][mt][3] * inv);
      *(uint2*)(Ps + prow +
                ((((mt * 2 + (quad >> 1)) ^ l8) << 3) + (quad & 1) * 4)) = w;
    }
  }
  __syncthreads();
  {
    size_t base0 = ((size_t)b * 2048 + q0 + sr) * 1024 + h * 64 + sg * 8;
    size_t base1 = base0 + (size_t)128 * 1024;
    *(uint4*)(y + base0)     = *(const uint4*)(Ps + slot0);
    *(uint4*)(y + base0 + 8) = *(const uint4*)(Ps + slot1);
    *(uint4*)(y + base1)     = *(const uint4*)(Ps + slot0 + 8192);
    *(uint4*)(y + base1 + 8) = *(const uint4*)(Ps + slot1 + 8192);
  }
}

// ---------------------------------------------------------------- launch
extern "C" void kernel_launch(void* const* d_in, const int* in_sizes, int n_in,
                              void* d_out, int out_size, void* d_ws, size_t ws_size,
                              hipStream_t stream) {
  const float* x     = (const float*)d_in[0];
  const float* w_in  = (const float*)d_in[1];
  const float* b_in  = (const float*)d_in[2];
  const float* w_out = (const float*)d_in[3];
  const float* b_out = (const float*)d_in[4];
  const int*   cmask = (const int*)d_in[5];

  char* ws = (char*)d_ws;
  unsigned short* x_bf     = (unsigned short*)(ws);               // 8192x1024  (16 MB)
  unsigned short* w_in_bf  = (unsigned short*)(ws + 16777216);    // 3072x1024  (6 MB)
  unsigned short* w_out_bf = (unsigned short*)(ws + 23068672);    // 1024x1024  (2 MB)
  unsigned short* qkv2_bf  = (unsigned short*)(ws + 25165824);    // 8192x2048 Q|K (32 MB)
  unsigned short* vt_bf    = (unsigned short*)(ws + 58720256);    // 64bh x 64d x 2048s (16 MB)
  unsigned short* y_bf     = (unsigned short*)(ws + 75497472);    // 8192x1024  (16 MB)

  const int ntot = (8192 + 3072 + 1024) * 1024;
  cvt_all<<<dim3(ntot / 4 / 256), 256, 0, stream>>>(x, w_in, w_out, x_bf, w_in_bf, w_out_bf);

  // QKV = x * w_in^T + b_in ; Q cols pre-scaled; Q|K -> qkv2 row-major, V -> vt transposed
  gemm_bt128<true, true><<<dim3(24, 64), 256, 0, stream>>>(
      x_bf, w_in_bf, b_in, qkv2_bf, vt_bf, 8192, 3072, 1024, 2048,
      0.18033688011112042f, 1024);

  // flash attention -> y_bf (8192 x 1024)
  attn<<<dim3(512), 512, 0, stream>>>(qkv2_bf, vt_bf, y_bf, cmask);

  // out = y * w_out^T + b_out -> fp32 d_out
  gemm_bt128<false, false><<<dim3(8, 64), 256, 0, stream>>>(
      y_bf, w_out_bf, b_out, d_out, nullptr, 8192, 1024, 1024, 1024, 1.0f, 0);
}

// Round 9
// 252.523 us; speedup vs baseline: 1.0376x; 1.0248x over previous
//
#include <hip/hip_runtime.h>

typedef __bf16 bf16x8 __attribute__((ext_vector_type(8)));
typedef float  f32x4  __attribute__((ext_vector_type(4)));
typedef unsigned int uint;

__device__ inline unsigned short f2bf(float f) {
  union { float f; unsigned int u; } v; v.f = f;
  unsigned int u = v.u;
  unsigned int r = u + 0x7FFF + ((u >> 16) & 1);   // RNE
  return (unsigned short)(r >> 16);
}

// pack two floats to packed bf16x2 with round-half-up (err <= 0.5 ulp)
__device__ inline uint pack_bf16_rhu(float a, float b) {
  uint ua = __builtin_bit_cast(uint, a) + 0x8000u;
  uint ub = __builtin_bit_cast(uint, b) + 0x8000u;
  return __builtin_amdgcn_perm(ub, ua, 0x07060302u);
}

__device__ inline void load_lds16(const unsigned short* g, unsigned short* l) {
  __builtin_amdgcn_global_load_lds(
      (const __attribute__((address_space(1))) uint*)(g),
      (__attribute__((address_space(3))) uint*)(l), 16, 0, 0);
}

// ---------------------------------------------------------------- fused convert
__device__ inline void cvt4(const float* in, unsigned short* out) {
  float4 f = *reinterpret_cast<const float4*>(in);
  ushort4 o;
  o.x = f2bf(f.x); o.y = f2bf(f.y); o.z = f2bf(f.z); o.w = f2bf(f.w);
  *reinterpret_cast<ushort4*>(out) = o;
}

__global__ void cvt_all(const float* __restrict__ x, const float* __restrict__ w_in,
                        const float* __restrict__ w_out,
                        unsigned short* __restrict__ x_bf,
                        unsigned short* __restrict__ w_in_bf,
                        unsigned short* __restrict__ w_out_bf) {
  const int n1 = 8192 * 1024, n2 = 3072 * 1024;
  int i = (blockIdx.x * blockDim.x + threadIdx.x) * 4;
  if (i < n1)            cvt4(x + i, x_bf + i);
  else if (i < n1 + n2)  cvt4(w_in + (i - n1), w_in_bf + (i - n1));
  else                   cvt4(w_out + (i - n1 - n2), w_out_bf + (i - n1 - n2));
}

// ---------------------------------------------------------------- GEMM  C = A * B^T + bias
// R2-verified m97 structure (single 32 KB buffer, stage-after, 2 barriers/tile)
// -- measured 68.8 us / 749 TF on gemm1; the structure ceiling for this shape.
// VSPLIT: cols < 2048 -> row-major Cout, cols >= 2048 (V) -> transposed vt[bh][d][s].
template<bool OUT_BF16, bool VSPLIT>
__global__ __launch_bounds__(256) void gemm_bt128(
    const unsigned short* __restrict__ A,
    const unsigned short* __restrict__ B,
    const float* __restrict__ bias,
    void* __restrict__ Cout,
    unsigned short* __restrict__ vt,
    int M, int N, int K, int ldc, float scale, int ncut)
{
  __shared__ __attribute__((aligned(16))) unsigned short As[128 * 64];
  __shared__ __attribute__((aligned(16))) unsigned short Bs[128 * 64];

  const int t    = threadIdx.x;
  const int wave = t >> 6, lane = t & 63;
  const int l16  = lane & 15, quad = lane >> 4;
  const int wr = wave >> 1, wc = wave & 1;
  const int m0 = blockIdx.y * 128, n0 = blockIdx.x * 128;
  const int l8 = l16 & 7;

  f32x4 acc[4][4] = {};

  for (int k0 = 0; k0 < K; k0 += 64) {
#pragma unroll
    for (int i = 0; i < 4; ++i) {
      int chunk = i * 256 + t;
      int row = chunk >> 3, cb = chunk & 7;
      int gcb = cb ^ (row & 7);
      load_lds16(A + (size_t)(m0 + row) * K + k0 + gcb * 8, As + chunk * 8);
    }
#pragma unroll
    for (int i = 0; i < 4; ++i) {
      int chunk = i * 256 + t;
      int row = chunk >> 3, cb = chunk & 7;
      int gcb = cb ^ (row & 7);
      load_lds16(B + (size_t)(n0 + row) * K + k0 + gcb * 8, Bs + chunk * 8);
    }
    __syncthreads();
#pragma unroll
    for (int ks = 0; ks < 2; ++ks) {
      bf16x8 af[4], bfr[4];
#pragma unroll
      for (int mt = 0; mt < 4; ++mt)
        af[mt] = *(const bf16x8*)(As + (wr * 64 + mt * 16 + l16) * 64 +
                                  (((ks * 4 + quad) ^ l8) << 3));
#pragma unroll
      for (int nt = 0; nt < 4; ++nt)
        bfr[nt] = *(const bf16x8*)(Bs + (wc * 64 + nt * 16 + l16) * 64 +
                                   (((ks * 4 + quad) ^ l8) << 3));
#pragma unroll
      for (int mt = 0; mt < 4; ++mt)
#pragma unroll
        for (int nt = 0; nt < 4; ++nt)
          acc[mt][nt] = __builtin_amdgcn_mfma_f32_16x16x32_bf16(af[mt], bfr[nt], acc[mt][nt], 0, 0, 0);
    }
    __syncthreads();
  }

#pragma unroll
  for (int nt = 0; nt < 4; ++nt) {
    int col = n0 + wc * 64 + nt * 16 + l16;
    float bv = bias[col];
    float mlt = (col < ncut) ? scale : 1.0f;
#pragma unroll
    for (int mt = 0; mt < 4; ++mt) {
      int row0 = m0 + wr * 64 + mt * 16 + quad * 4;
      float v0 = (acc[mt][nt][0] + bv) * mlt;
      float v1 = (acc[mt][nt][1] + bv) * mlt;
      float v2 = (acc[mt][nt][2] + bv) * mlt;
      float v3 = (acc[mt][nt][3] + bv) * mlt;
      if (VSPLIT && col >= 2048) {
        int d = col - 2048, h = d >> 6, dd = d & 63;
        int bb = row0 >> 11, s = row0 & 2047;
        uint2 w;
        w.x = pack_bf16_rhu(v0, v1);
        w.y = pack_bf16_rhu(v2, v3);
        *(uint2*)(vt + ((size_t)((bb * 16 + h) * 64 + dd) * 2048 + s)) = w;
      } else {
#pragma unroll
        for (int r = 0; r < 4; ++r) {
          float v = (r == 0) ? v0 : (r == 1) ? v1 : (r == 2) ? v2 : v3;
          if (OUT_BF16)
            ((unsigned short*)Cout)[(size_t)(row0 + r) * ldc + col] = f2bf(v);
          else
            ((float*)Cout)[(size_t)(row0 + r) * ldc + col] = v;
        }
      }
    }
  }
}

// ---------------------------------------------------------------- flash attention
// 64-row Q-tile, 4 waves (256 threads) -- R0's proven per-block code -- with
// R2's intra-block pairing and single-barrier K/V double-buffer.
// Block (k, bh) processes qt = 31-k then qt = k  ->  (31-k+1)+(k+1) = 34 KV
// tiles per block, UNIFORM (all blocks finish together; heavy half first).
// 16 k-pairs x 64 bh = 1024 blocks; LDS 8+16+16 = 40 KB -> EXACTLY 4 blocks/CU
// = 16 waves/CU in 4 independent barrier domains (R2 had same waves in only 2).
// All LDS tiles unpadded, unified XOR granule swizzle:
//   slot(row, G) = row*64 + ((G ^ (row&7)) << 3)
__global__ __launch_bounds__(256) void attn(
    const unsigned short* __restrict__ qkv2,   // (B*S) x 2048 : Q|K
    const unsigned short* __restrict__ vt,     // [bh][d][s]
    unsigned short* __restrict__ y,
    const int* __restrict__ flag)
{
  __shared__ __attribute__((aligned(16))) unsigned short Qs[64 * 64];       // 8 KB, reused as Ps
  __shared__ __attribute__((aligned(16))) unsigned short Ks[2][64 * 64];    // 16 KB
  __shared__ __attribute__((aligned(16))) unsigned short Vs[2][64 * 64];    // 16 KB

  const int t    = threadIdx.x;
  const int wave = t >> 6, lane = t & 63;          // wave 0..3
  const int l16  = lane & 15, quad = lane >> 4;
  const int l8   = l16 & 7;
  const int idx  = blockIdx.x;
  const int bh   = idx & 63;
  const int kp   = idx >> 6;                       // 0..15
  const int b = bh >> 4, h = bh & 15;
  const int causal = flag[0];

  const unsigned short* Qg  = qkv2 + (size_t)b * 2048 * 2048 + h * 64;
  const unsigned short* Kg  = Qg + 1024;
  const unsigned short* Vtg = vt + (size_t)bh * 64 * 2048;

  // staging coords (64 rows x 8 granules, 2 granules per thread)
  const int sr = t >> 2, sg = (t & 3) * 2;
  const int slot0 = sr * 64 + (((sg    ) ^ (sr & 7)) << 3);
  const int slot1 = sr * 64 + (((sg + 1) ^ (sr & 7)) << 3);
  // V^T staging: row d = sr, granules vb and vb+4
  const int vb = t & 3;
  const int vslot0 = sr * 64 + ((( vb    ) ^ (sr & 7)) << 3);
  const int vslot1 = sr * 64 + (((vb + 4) ^ (sr & 7)) << 3);
  const unsigned short* vrow = Vtg + (size_t)sr * 2048;
  const unsigned short* krow = Kg + (size_t)sr * 2048 + sg * 8;

  unsigned short* Ps = Qs;

  for (int half = 0; half < 2; ++half) {
    const int qt = half ? kp : (31 - kp);     // heavy tile first
    const int q0 = qt * 64;
    const int jmax = causal ? qt : 31;

    // ---- prefetch K/V tile 0; stage Q tile (swizzled)
    uint4 kreg0 = *(const uint4*)krow;
    uint4 kreg1 = *(const uint4*)(krow + 8);
    uint4 vreg0 = *(const uint4*)(vrow + vb * 8);
    uint4 vreg1 = *(const uint4*)(vrow + vb * 8 + 32);
    {
      const unsigned short* src = Qg + (size_t)(q0 + sr) * 2048 + sg * 8;
      *(uint4*)(Qs + slot0) = *(const uint4*)src;
      *(uint4*)(Qs + slot1) = *(const uint4*)(src + 8);
    }
    __syncthreads();
    bf16x8 qf[2];
    qf[0] = *(const bf16x8*)(Qs + (wave * 16 + l16) * 64 + (((0 + quad) ^ l8) << 3));
    qf[1] = *(const bf16x8*)(Qs + (wave * 16 + l16) * 64 + (((4 + quad) ^ l8) << 3));
    __syncthreads();                 // Qs becomes Ps

    // ---- prologue: write tile 0 to buf0, prefetch tile 1
    *(uint4*)(Ks[0] + slot0)  = kreg0;
    *(uint4*)(Ks[0] + slot1)  = kreg1;
    *(uint4*)(Vs[0] + vslot0) = vreg0;
    *(uint4*)(Vs[0] + vslot1) = vreg1;
    if (jmax > 0) {
      kreg0 = *(const uint4*)(krow + (size_t)64 * 2048);
      kreg1 = *(const uint4*)(krow + (size_t)64 * 2048 + 8);
      vreg0 = *(const uint4*)(vrow + 64 + vb * 8);
      vreg1 = *(const uint4*)(vrow + 64 + vb * 8 + 32);
    }
    __syncthreads();

    f32x4 ot[4] = {};
    float l_lane = 0.f;
    const int q_glob = q0 + wave * 16 + l16;

    for (int j = 0; j <= jmax; ++j) {
      const int cur = j & 1;
      // write next tile (regs prefetched a full iteration ago), prefetch j+2
      if (j < jmax) {
        *(uint4*)(Ks[cur ^ 1] + slot0)  = kreg0;
        *(uint4*)(Ks[cur ^ 1] + slot1)  = kreg1;
        *(uint4*)(Vs[cur ^ 1] + vslot0) = vreg0;
        *(uint4*)(Vs[cur ^ 1] + vslot1) = vreg1;
        if (j + 1 < jmax) {
          const int kvn = (j + 2) * 64;
          kreg0 = *(const uint4*)(krow + (size_t)kvn * 2048);
          kreg1 = *(const uint4*)(krow + (size_t)kvn * 2048 + 8);
          vreg0 = *(const uint4*)(vrow + kvn + vb * 8);
          vreg1 = *(const uint4*)(vrow + kvn + vb * 8 + 32);
        }
      }

      // ---- S^T = K * Q^T : st[mt] is 16(kv) x 16(q)
      f32x4 st[4] = {};
      __builtin_amdgcn_s_setprio(1);
#pragma unroll
      for (int ks = 0; ks < 2; ++ks) {
#pragma unroll
        for (int mt = 0; mt < 4; ++mt) {
          bf16x8 kf = *(const bf16x8*)(Ks[cur] + (mt * 16 + l16) * 64 +
                                       (((ks * 4 + quad) ^ l8) << 3));
          st[mt] = __builtin_amdgcn_mfma_f32_16x16x32_bf16(kf, qf[ks], st[mt], 0, 0, 0);
        }
      }
      __builtin_amdgcn_s_setprio(0);

      // ---- softmax (pre-scaled scores; no max-sub), pack P (swizzled b64 writes)
      const bool diag = (causal != 0) && (j == qt);
      const int kv0 = j << 6;
#pragma unroll
      for (int mt = 0; mt < 4; ++mt) {
        float p[4];
#pragma unroll
        for (int r = 0; r < 4; ++r) {
          float pv = __builtin_amdgcn_exp2f(st[mt][r]);
          if (diag) {
            int kv = kv0 + mt * 16 + quad * 4 + r;
            if (kv > q_glob) pv = 0.f;
          }
          p[r] = pv;
        }
        l_lane += (p[0] + p[1]) + (p[2] + p[3]);
        uint2 w;
        w.x = pack_bf16_rhu(p[0], p[1]);
        w.y = pack_bf16_rhu(p[2], p[3]);
        *(uint2*)(Ps + (wave * 16 + l16) * 64 +
                  ((((mt * 2 + (quad >> 1)) ^ l8) << 3) + (quad & 1) * 4)) = w;
      }
      __threadfence_block();

      // ---- O^T += V^T * P^T
      __builtin_amdgcn_s_setprio(1);
#pragma unroll
      for (int ks = 0; ks < 2; ++ks) {
        bf16x8 pf = *(const bf16x8*)(Ps + (wave * 16 + l16) * 64 +
                                     (((ks * 4 + quad) ^ l8) << 3));
#pragma unroll
        for (int mt = 0; mt < 4; ++mt) {
          bf16x8 vf = *(const bf16x8*)(Vs[cur] + (mt * 16 + l16) * 64 +
                                       (((ks * 4 + quad) ^ l8) << 3));
          ot[mt] = __builtin_amdgcn_mfma_f32_16x16x32_bf16(vf, pf, ot[mt], 0, 0, 0);
        }
      }
      __builtin_amdgcn_s_setprio(0);
      __syncthreads();
    }

    // ---- finalize
    l_lane += __shfl_xor(l_lane, 16);
    l_lane += __shfl_xor(l_lane, 32);
    float inv = 1.f / l_lane;

#pragma unroll
    for (int mt = 0; mt < 4; ++mt) {
      uint2 w;
      w.x = pack_bf16_rhu(ot[mt][0] * inv, ot[mt][1] * inv);
      w.y = pack_bf16_rhu(ot[mt][2] * inv, ot[mt][3] * inv);
      *(uint2*)(Ps + (wave * 16 + l16) * 64 +
                ((((mt * 2 + (quad >> 1)) ^ l8) << 3) + (quad & 1) * 4)) = w;
    }
    __syncthreads();
    {
      size_t base = ((size_t)b * 2048 + q0 + sr) * 1024 + h * 64 + sg * 8;
      *(uint4*)(y + base)     = *(const uint4*)(Ps + slot0);
      *(uint4*)(y + base + 8) = *(const uint4*)(Ps + slot1);
    }
    __syncthreads();   // Ps fully consumed before next half re-stages Qs
  }
}

// ---------------------------------------------------------------- launch
extern "C" void kernel_launch(void* const* d_in, const int* in_sizes, int n_in,
                              void* d_out, int out_size, void* d_ws, size_t ws_size,
                              hipStream_t stream) {
  const float* x     = (const float*)d_in[0];
  const float* w_in  = (const float*)d_in[1];
  const float* b_in  = (const float*)d_in[2];
  const float* w_out = (const float*)d_in[3];
  const float* b_out = (const float*)d_in[4];
  const int*   cmask = (const int*)d_in[5];

  char* ws = (char*)d_ws;
  unsigned short* x_bf     = (unsigned short*)(ws);               // 8192x1024  (16 MB)
  unsigned short* w_in_bf  = (unsigned short*)(ws + 16777216);    // 3072x1024  (6 MB)
  unsigned short* w_out_bf = (unsigned short*)(ws + 23068672);    // 1024x1024  (2 MB)
  unsigned short* qkv2_bf  = (unsigned short*)(ws + 25165824);    // 8192x2048 Q|K (32 MB)
  unsigned short* vt_bf    = (unsigned short*)(ws + 58720256);    // 64bh x 64d x 2048s (16 MB)
  unsigned short* y_bf     = (unsigned short*)(ws + 75497472);    // 8192x1024  (16 MB)

  const int ntot = (8192 + 3072 + 1024) * 1024;
  cvt_all<<<dim3(ntot / 4 / 256), 256, 0, stream>>>(x, w_in, w_out, x_bf, w_in_bf, w_out_bf);

  // QKV = x * w_in^T + b_in ; Q cols pre-scaled; Q|K -> qkv2 row-major, V -> vt transposed
  gemm_bt128<true, true><<<dim3(24, 64), 256, 0, stream>>>(
      x_bf, w_in_bf, b_in, qkv2_bf, vt_bf, 8192, 3072, 1024, 2048,
      0.18033688011112042f, 1024);

  // flash attention -> y_bf (8192 x 1024): 1024 blocks, 4 blocks/CU, uniform 34 tiles
  attn<<<dim3(1024), 256, 0, stream>>>(qkv2_bf, vt_bf, y_bf, cmask);

  // out = y * w_out^T + b_out -> fp32 d_out
  gemm_bt128<false, false><<<dim3(8, 64), 256, 0, stream>>>(
      y_bf, w_out_bf, b_out, d_out, nullptr, 8192, 1024, 1024, 1024, 1.0f, 0);
}

// Round 10
// 244.670 us; speedup vs baseline: 1.0709x; 1.0321x over previous
//
#include <hip/hip_runtime.h>

typedef __bf16 bf16x8 __attribute__((ext_vector_type(8)));
typedef float  f32x4  __attribute__((ext_vector_type(4)));
typedef unsigned int uint;

__device__ inline unsigned short f2bf(float f) {
  union { float f; unsigned int u; } v; v.f = f;
  unsigned int u = v.u;
  unsigned int r = u + 0x7FFF + ((u >> 16) & 1);   // RNE
  return (unsigned short)(r >> 16);
}

// pack two floats to packed bf16x2 with round-half-up (err <= 0.5 ulp)
__device__ inline uint pack_bf16_rhu(float a, float b) {
  uint ua = __builtin_bit_cast(uint, a) + 0x8000u;
  uint ub = __builtin_bit_cast(uint, b) + 0x8000u;
  return __builtin_amdgcn_perm(ub, ua, 0x07060302u);
}

__device__ inline void load_lds16(const unsigned short* g, unsigned short* l) {
  __builtin_amdgcn_global_load_lds(
      (const __attribute__((address_space(1))) uint*)(g),
      (__attribute__((address_space(3))) uint*)(l), 16, 0, 0);
}

// ---------------------------------------------------------------- fused convert
__device__ inline void cvt4(const float* in, unsigned short* out) {
  float4 f = *reinterpret_cast<const float4*>(in);
  ushort4 o;
  o.x = f2bf(f.x); o.y = f2bf(f.y); o.z = f2bf(f.z); o.w = f2bf(f.w);
  *reinterpret_cast<ushort4*>(out) = o;
}

__global__ void cvt_all(const float* __restrict__ x, const float* __restrict__ w_in,
                        const float* __restrict__ w_out,
                        unsigned short* __restrict__ x_bf,
                        unsigned short* __restrict__ w_in_bf,
                        unsigned short* __restrict__ w_out_bf) {
  const int n1 = 8192 * 1024, n2 = 3072 * 1024;
  int i = (blockIdx.x * blockDim.x + threadIdx.x) * 4;
  if (i < n1)            cvt4(x + i, x_bf + i);
  else if (i < n1 + n2)  cvt4(w_in + (i - n1), w_in_bf + (i - n1));
  else                   cvt4(w_out + (i - n1 - n2), w_out_bf + (i - n1 - n2));
}

// ---------------------------------------------------------------- GEMM  C = A * B^T + bias
// R2-verified m97 structure (single 32 KB buffer, stage-after, 2 barriers/tile)
// -- measured 68.8 us / 749 TF on gemm1; the structure ceiling for this shape.
// VSPLIT: cols < 2048 -> row-major Cout, cols >= 2048 (V) -> transposed vt[bh][d][s].
template<bool OUT_BF16, bool VSPLIT>
__global__ __launch_bounds__(256) void gemm_bt128(
    const unsigned short* __restrict__ A,
    const unsigned short* __restrict__ B,
    const float* __restrict__ bias,
    void* __restrict__ Cout,
    unsigned short* __restrict__ vt,
    int M, int N, int K, int ldc, float scale, int ncut)
{
  __shared__ __attribute__((aligned(16))) unsigned short As[128 * 64];
  __shared__ __attribute__((aligned(16))) unsigned short Bs[128 * 64];

  const int t    = threadIdx.x;
  const int wave = t >> 6, lane = t & 63;
  const int l16  = lane & 15, quad = lane >> 4;
  const int wr = wave >> 1, wc = wave & 1;
  const int m0 = blockIdx.y * 128, n0 = blockIdx.x * 128;
  const int l8 = l16 & 7;

  f32x4 acc[4][4] = {};

  for (int k0 = 0; k0 < K; k0 += 64) {
#pragma unroll
    for (int i = 0; i < 4; ++i) {
      int chunk = i * 256 + t;
      int row = chunk >> 3, cb = chunk & 7;
      int gcb = cb ^ (row & 7);
      load_lds16(A + (size_t)(m0 + row) * K + k0 + gcb * 8, As + chunk * 8);
    }
#pragma unroll
    for (int i = 0; i < 4; ++i) {
      int chunk = i * 256 + t;
      int row = chunk >> 3, cb = chunk & 7;
      int gcb = cb ^ (row & 7);
      load_lds16(B + (size_t)(n0 + row) * K + k0 + gcb * 8, Bs + chunk * 8);
    }
    __syncthreads();
#pragma unroll
    for (int ks = 0; ks < 2; ++ks) {
      bf16x8 af[4], bfr[4];
#pragma unroll
      for (int mt = 0; mt < 4; ++mt)
        af[mt] = *(const bf16x8*)(As + (wr * 64 + mt * 16 + l16) * 64 +
                                  (((ks * 4 + quad) ^ l8) << 3));
#pragma unroll
      for (int nt = 0; nt < 4; ++nt)
        bfr[nt] = *(const bf16x8*)(Bs + (wc * 64 + nt * 16 + l16) * 64 +
                                   (((ks * 4 + quad) ^ l8) << 3));
#pragma unroll
      for (int mt = 0; mt < 4; ++mt)
#pragma unroll
        for (int nt = 0; nt < 4; ++nt)
          acc[mt][nt] = __builtin_amdgcn_mfma_f32_16x16x32_bf16(af[mt], bfr[nt], acc[mt][nt], 0, 0, 0);
    }
    __syncthreads();
  }

#pragma unroll
  for (int nt = 0; nt < 4; ++nt) {
    int col = n0 + wc * 64 + nt * 16 + l16;
    float bv = bias[col];
    float mlt = (col < ncut) ? scale : 1.0f;
#pragma unroll
    for (int mt = 0; mt < 4; ++mt) {
      int row0 = m0 + wr * 64 + mt * 16 + quad * 4;
      float v0 = (acc[mt][nt][0] + bv) * mlt;
      float v1 = (acc[mt][nt][1] + bv) * mlt;
      float v2 = (acc[mt][nt][2] + bv) * mlt;
      float v3 = (acc[mt][nt][3] + bv) * mlt;
      if (VSPLIT && col >= 2048) {
        int d = col - 2048, h = d >> 6, dd = d & 63;
        int bb = row0 >> 11, s = row0 & 2047;
        uint2 w;
        w.x = pack_bf16_rhu(v0, v1);
        w.y = pack_bf16_rhu(v2, v3);
        *(uint2*)(vt + ((size_t)((bb * 16 + h) * 64 + dd) * 2048 + s)) = w;
      } else {
#pragma unroll
        for (int r = 0; r < 4; ++r) {
          float v = (r == 0) ? v0 : (r == 1) ? v1 : (r == 2) ? v2 : v3;
          if (OUT_BF16)
            ((unsigned short*)Cout)[(size_t)(row0 + r) * ldc + col] = f2bf(v);
          else
            ((float*)Cout)[(size_t)(row0 + r) * ldc + col] = v;
        }
      }
    }
  }
}

// ---------------------------------------------------------------- flash attention
// R2-best config (128-row Q-tile, 8 waves, paired qt -> uniform 34 tiles/block,
// 512 blocks, K/V dbuf, one barrier per tile) + DMA STAGING:
// K/V staged via global_load_lds with PRE-SWIZZLED global source and linear
// LDS dest (the gemm-verified rule-21 involution) -- removes the per-tile
// VGPR round-trip (2 uint4 loads + 2 ds_write_b128 + addr/wait chains/thread).
// DMA for tile j+1 issued at tile-j start into the free buffer; __syncthreads
// at tile end drains vmcnt -> full compute phase of flight.
// LDS 48 KB -> 3 blocks/CU = 24 waves/CU.
// slot(row, G) = row*64 + ((G ^ (row&7)) << 3); DMA chunk c = t: phys granule
// g=t&7 at row r=t>>3 receives logical granule g^(r&7).
__global__ __launch_bounds__(512) void attn(
    const unsigned short* __restrict__ qkv2,   // (B*S) x 2048 : Q|K
    const unsigned short* __restrict__ vt,     // [bh][d][s]
    unsigned short* __restrict__ y,
    const int* __restrict__ flag)
{
  __shared__ __attribute__((aligned(16))) unsigned short Qs[128 * 64];      // 16 KB, reused as Ps
  __shared__ __attribute__((aligned(16))) unsigned short Ks[2][64 * 64];    // 16 KB
  __shared__ __attribute__((aligned(16))) unsigned short Vs[2][64 * 64];    // 16 KB

  const int t    = threadIdx.x;
  const int wave = t >> 6, lane = t & 63;
  const int l16  = lane & 15, quad = lane >> 4;
  const int l8   = l16 & 7;
  const int idx  = blockIdx.x;
  const int bh   = idx & 63;
  const int pair = idx >> 6;                  // 0..7
  const int b = bh >> 4, h = bh & 15;
  const int causal = flag[0];

  const unsigned short* Qg  = qkv2 + (size_t)b * 2048 * 2048 + h * 64;
  const unsigned short* Kg  = Qg + 1024;
  const unsigned short* Vtg = vt + (size_t)bh * 64 * 2048;

  // Q staging coords (128 rows x 8 granules, 2 granules per thread, reg-staged)
  const int sr = t >> 2, sg = (t & 3) * 2;
  const int slot0 = sr * 64 + (((sg    ) ^ (sr & 7)) << 3);
  const int slot1 = sr * 64 + (((sg + 1) ^ (sr & 7)) << 3);
  // K / V^T DMA staging: chunk c = t -> row kr = t>>3, phys granule kg = t&7,
  // pre-swizzled source granule kgs = kg ^ (kr&7); LDS dest linear = t*8.
  const int kr  = t >> 3, kg = t & 7;
  const int kgs = kg ^ (kr & 7);
  const unsigned short* ksrc0 = Kg  + (size_t)kr * 2048 + kgs * 8;   // + kv0*2048
  const unsigned short* vsrc0 = Vtg + (size_t)kr * 2048 + kgs * 8;   // + kv0
  const int dofs = t * 8;

  unsigned short* Ps = Qs;

  for (int half = 0; half < 2; ++half) {
    const int qt = half ? pair : (15 - pair);   // heavy tile first
    const int q0 = qt * 128;
    const int jmax = causal ? 2 * qt + 1 : 31;

    // ---- issue DMA tile 0 -> buf0, then stage Q (swizzled reg path)
    load_lds16(ksrc0, Ks[0] + dofs);
    load_lds16(vsrc0, Vs[0] + dofs);
    {
      const unsigned short* src = Qg + (size_t)(q0 + sr) * 2048 + sg * 8;
      *(uint4*)(Qs + slot0) = *(const uint4*)src;
      *(uint4*)(Qs + slot1) = *(const uint4*)(src + 8);
    }
    __syncthreads();                 // drains DMA0 + Q writes
    bf16x8 qf[2];
    qf[0] = *(const bf16x8*)(Qs + (wave * 16 + l16) * 64 + (((0 + quad) ^ l8) << 3));
    qf[1] = *(const bf16x8*)(Qs + (wave * 16 + l16) * 64 + (((4 + quad) ^ l8) << 3));
    __syncthreads();                 // Qs becomes Ps

    f32x4 ot[4] = {};
    float l_lane = 0.f;
    const int q_glob = q0 + wave * 16 + l16;
    const int wq_max = q0 + wave * 16 + 15;     // last q row owned by this wave

    for (int j = 0; j <= jmax; ++j) {
      const int cur = j & 1;
      // issue DMA for tile j+1 into the free buffer (drained by this tile's
      // ending barrier; buf^1's previous readers all passed the last barrier)
      if (j < jmax) {
        const int kvn = (j + 1) << 6;
        load_lds16(ksrc0 + (size_t)kvn * 2048, Ks[cur ^ 1] + dofs);
        load_lds16(vsrc0 + kvn,               Vs[cur ^ 1] + dofs);
      }

      // waves whose 16 q rows lie entirely above this KV tile skip compute
      const bool active = !causal || ((j << 6) <= wq_max);
      if (active) {
        // ---- S^T = K * Q^T : st[mt] is 16(kv) x 16(q)
        f32x4 st[4] = {};
        __builtin_amdgcn_s_setprio(1);
#pragma unroll
        for (int ks = 0; ks < 2; ++ks) {
#pragma unroll
          for (int mt = 0; mt < 4; ++mt) {
            bf16x8 kf = *(const bf16x8*)(Ks[cur] + (mt * 16 + l16) * 64 +
                                         (((ks * 4 + quad) ^ l8) << 3));
            st[mt] = __builtin_amdgcn_mfma_f32_16x16x32_bf16(kf, qf[ks], st[mt], 0, 0, 0);
          }
        }
        __builtin_amdgcn_s_setprio(0);

        // ---- softmax (pre-scaled scores; no max-sub), pack P (swizzled b64 writes)
        const int kv0 = j << 6;
        const bool diag = (causal != 0) && (kv0 + 63 > q_glob);
#pragma unroll
        for (int mt = 0; mt < 4; ++mt) {
          float p[4];
#pragma unroll
          for (int r = 0; r < 4; ++r) {
            float pv = __builtin_amdgcn_exp2f(st[mt][r]);
            if (diag) {
              int kv = kv0 + mt * 16 + quad * 4 + r;
              if (kv > q_glob) pv = 0.f;
            }
            p[r] = pv;
          }
          l_lane += (p[0] + p[1]) + (p[2] + p[3]);
          uint2 w;
          w.x = pack_bf16_rhu(p[0], p[1]);
          w.y = pack_bf16_rhu(p[2], p[3]);
          *(uint2*)(Ps + (wave * 16 + l16) * 64 +
                    ((((mt * 2 + (quad >> 1)) ^ l8) << 3) + (quad & 1) * 4)) = w;
        }
        __threadfence_block();

        // ---- O^T += V^T * P^T
        __builtin_amdgcn_s_setprio(1);
#pragma unroll
        for (int ks = 0; ks < 2; ++ks) {
          bf16x8 pf = *(const bf16x8*)(Ps + (wave * 16 + l16) * 64 +
                                       (((ks * 4 + quad) ^ l8) << 3));
#pragma unroll
          for (int mt = 0; mt < 4; ++mt) {
            bf16x8 vf = *(const bf16x8*)(Vs[cur] + (mt * 16 + l16) * 64 +
                                         (((ks * 4 + quad) ^ l8) << 3));
            ot[mt] = __builtin_amdgcn_mfma_f32_16x16x32_bf16(vf, pf, ot[mt], 0, 0, 0);
          }
        }
        __builtin_amdgcn_s_setprio(0);
      }
      __syncthreads();               // drains DMA(j+1) + releases buf cur
    }

    // ---- finalize
    l_lane += __shfl_xor(l_lane, 16);
    l_lane += __shfl_xor(l_lane, 32);
    float inv = 1.f / l_lane;

#pragma unroll
    for (int mt = 0; mt < 4; ++mt) {
      uint2 w;
      w.x = pack_bf16_rhu(ot[mt][0] * inv, ot[mt][1] * inv);
      w.y = pack_bf16_rhu(ot[mt][2] * inv, ot[mt][3] * inv);
      *(uint2*)(Ps + (wave * 16 + l16) * 64 +
                ((((mt * 2 + (quad >> 1)) ^ l8) << 3) + (quad & 1) * 4)) = w;
    }
    __syncthreads();
    {
      size_t base = ((size_t)b * 2048 + q0 + sr) * 1024 + h * 64 + sg * 8;
      *(uint4*)(y + base)     = *(const uint4*)(Ps + slot0);
      *(uint4*)(y + base + 8) = *(const uint4*)(Ps + slot1);
    }
    __syncthreads();   // Ps fully consumed before next half re-stages Qs
  }
}

// ---------------------------------------------------------------- launch
extern "C" void kernel_launch(void* const* d_in, const int* in_sizes, int n_in,
                              void* d_out, int out_size, void* d_ws, size_t ws_size,
                              hipStream_t stream) {
  const float* x     = (const float*)d_in[0];
  const float* w_in  = (const float*)d_in[1];
  const float* b_in  = (const float*)d_in[2];
  const float* w_out = (const float*)d_in[3];
  const float* b_out = (const float*)d_in[4];
  const int*   cmask = (const int*)d_in[5];

  char* ws = (char*)d_ws;
  unsigned short* x_bf     = (unsigned short*)(ws);               // 8192x1024  (16 MB)
  unsigned short* w_in_bf  = (unsigned short*)(ws + 16777216);    // 3072x1024  (6 MB)
  unsigned short* w_out_bf = (unsigned short*)(ws + 23068672);    // 1024x1024  (2 MB)
  unsigned short* qkv2_bf  = (unsigned short*)(ws + 25165824);    // 8192x2048 Q|K (32 MB)
  unsigned short* vt_bf    = (unsigned short*)(ws + 58720256);    // 64bh x 64d x 2048s (16 MB)
  unsigned short* y_bf     = (unsigned short*)(ws + 75497472);    // 8192x1024  (16 MB)

  const int ntot = (8192 + 3072 + 1024) * 1024;
  cvt_all<<<dim3(ntot / 4 / 256), 256, 0, stream>>>(x, w_in, w_out, x_bf, w_in_bf, w_out_bf);

  // QKV = x * w_in^T + b_in ; Q cols pre-scaled; Q|K -> qkv2 row-major, V -> vt transposed
  gemm_bt128<true, true><<<dim3(24, 64), 256, 0, stream>>>(
      x_bf, w_in_bf, b_in, qkv2_bf, vt_bf, 8192, 3072, 1024, 2048,
      0.18033688011112042f, 1024);

  // flash attention -> y_bf (8192 x 1024): 512 blocks, uniform 34 tiles/block
  attn<<<dim3(512), 512, 0, stream>>>(qkv2_bf, vt_bf, y_bf, cmask);

  // out = y * w_out^T + b_out -> fp32 d_out
  gemm_bt128<false, false><<<dim3(8, 64), 256, 0, stream>>>(
      y_bf, w_out_bf, b_out, d_out, nullptr, 8192, 1024, 1024, 1024, 1.0f, 0);
}